// Round 4
// baseline (278.231 us; speedup 1.0000x reference)
//
#include <hip/hip_runtime.h>
#include <stdint.h>

#define N_NODES 50000
#define N_EDGES 800000
#define D_IN 128
#define H1 96
#define H1P 48   // packed bf16 pairs per node
#define H2 64
#define GEMM_NODES 32
#define SCAN_BLK 256
#define N_SBLK ((N_NODES + SCAN_BLK - 1) / SCAN_BLK)   // 196

__device__ __forceinline__ uint16_t f2bf(float f) {
    uint32_t u = __float_as_uint(f);
    uint32_t r = (u + 0x7FFFu + ((u >> 16) & 1u)) >> 16;  // RTN-even
    return (uint16_t)r;
}
__device__ __forceinline__ float bf_lo(uint32_t v) { return __uint_as_float(v << 16); }
__device__ __forceinline__ float bf_hi(uint32_t v) { return __uint_as_float(v & 0xFFFF0000u); }

// ---------------- degree histogram (int in-degree; +1 self-loop applied later) ----------
__global__ void count_deg_kernel(const int* __restrict__ dst, int* __restrict__ deg) {
    int i = blockIdx.x * blockDim.x + threadIdx.x;
    int stride = gridDim.x * blockDim.x;
    for (int e = i; e < N_EDGES; e += stride)
        atomicAdd(&deg[dst[e]], 1);
}

// ---------------- 3-phase device-wide exclusive scan ----------------
__global__ __launch_bounds__(SCAN_BLK) void deg_part_kernel(const int* __restrict__ deg,
                                                            int* __restrict__ block_sums) {
    __shared__ int s[SCAN_BLK];
    int t = threadIdx.x;
    int i = blockIdx.x * SCAN_BLK + t;
    s[t] = (i < N_NODES) ? deg[i] : 0;
    __syncthreads();
    for (int off = SCAN_BLK / 2; off > 0; off >>= 1) {
        if (t < off) s[t] += s[t + off];
        __syncthreads();
    }
    if (t == 0) block_sums[blockIdx.x] = s[0];
}

__global__ __launch_bounds__(SCAN_BLK) void block_scan_kernel(int* __restrict__ block_sums) {
    __shared__ int s[SCAN_BLK];
    int t = threadIdx.x;
    int v = (t < N_SBLK) ? block_sums[t] : 0;
    s[t] = v;
    __syncthreads();
    for (int off = 1; off < SCAN_BLK; off <<= 1) {
        int u = (t >= off) ? s[t - off] : 0;
        __syncthreads();
        s[t] += u;
        __syncthreads();
    }
    if (t < N_SBLK) block_sums[t] = s[t] - v;  // exclusive
}

__global__ __launch_bounds__(SCAN_BLK) void deg_scan_kernel(const int* __restrict__ deg,
                                                            const int* __restrict__ block_off,
                                                            int* __restrict__ row_start,
                                                            int* __restrict__ cursor,
                                                            float* __restrict__ dinv) {
    __shared__ int s[SCAN_BLK];
    int t = threadIdx.x;
    int i = blockIdx.x * SCAN_BLK + t;
    int v = (i < N_NODES) ? deg[i] : 0;
    s[t] = v;
    __syncthreads();
    for (int off = 1; off < SCAN_BLK; off <<= 1) {
        int u = (t >= off) ? s[t - off] : 0;
        __syncthreads();
        s[t] += u;
        __syncthreads();
    }
    int excl = s[t] - v + block_off[blockIdx.x];
    if (i < N_NODES) {
        row_start[i] = excl;
        cursor[i] = excl;
        dinv[i] = rsqrtf((float)v + 1.0f);  // +1 self-loop
    }
    if (i == 0) row_start[N_NODES] = N_EDGES;
}

// ---------------- scatter edges into CSR (index-only atomics) ----------------
__global__ void scatter_kernel(const int* __restrict__ src, const int* __restrict__ dst,
                               int* __restrict__ cursor, int* __restrict__ sorted_src) {
    int i = blockIdx.x * blockDim.x + threadIdx.x;
    int stride = gridDim.x * blockDim.x;
    for (int e = i; e < N_EDGES; e += stride) {
        int d = dst[e];
        int pos = atomicAdd(&cursor[d], 1);
        sorted_src[pos] = src[e];
    }
}

// ---------------- hs(bf16) = (x @ W1) * dinv[n] ----------------
__global__ __launch_bounds__(256) void gemm_kernel(const float* __restrict__ x,
                                                   const float* __restrict__ W1,
                                                   const float* __restrict__ dinv,
                                                   uint16_t* __restrict__ hs) {
    __shared__ float sW[D_IN * H1];          // 48 KB
    __shared__ float sx[GEMM_NODES * D_IN];  // 16 KB
    int tid = threadIdx.x;

    for (int i = tid; i < D_IN * H1 / 4; i += 256)
        ((float4*)sW)[i] = ((const float4*)W1)[i];

    int base = blockIdx.x * GEMM_NODES;
    const float4* x4 = (const float4*)x;
    for (int i = tid; i < GEMM_NODES * D_IN / 4; i += 256) {
        int n = base + i / (D_IN / 4);
        if (n < N_NODES) ((float4*)sx)[i] = x4[(size_t)base * (D_IN / 4) + i];
    }
    __syncthreads();

    int fg = tid & 31;
    int ng = tid >> 5;

    float acc[4][3];
#pragma unroll
    for (int i = 0; i < 4; ++i)
#pragma unroll
        for (int j = 0; j < 3; ++j) acc[i][j] = 0.0f;

#pragma unroll 4
    for (int k = 0; k < D_IN; ++k) {
        float w0 = sW[k * H1 + fg];
        float w1 = sW[k * H1 + fg + 32];
        float w2 = sW[k * H1 + fg + 64];
#pragma unroll
        for (int i = 0; i < 4; ++i) {
            float xv = sx[(ng * 4 + i) * D_IN + k];
            acc[i][0] = fmaf(xv, w0, acc[i][0]);
            acc[i][1] = fmaf(xv, w1, acc[i][1]);
            acc[i][2] = fmaf(xv, w2, acc[i][2]);
        }
    }

#pragma unroll
    for (int i = 0; i < 4; ++i) {
        int n = base + ng * 4 + i;
        if (n < N_NODES) {
            float dv = dinv[n];
            hs[(size_t)n * H1 + fg]      = f2bf(acc[i][0] * dv);
            hs[(size_t)n * H1 + fg + 32] = f2bf(acc[i][1] * dv);
            hs[(size_t)n * H1 + fg + 64] = f2bf(acc[i][2] * dv);
        }
    }
}

// ---------------- fused pull-aggregate + ReLU + sum-pool ----------------
// One wave per node; lane j<48 owns packed features (2j, 2j+1) as one uint32.
// row_start/sorted_src/dinv addresses are wave-uniform -> scalarized loads.
__global__ __launch_bounds__(256) void agg_pool_kernel(const uint32_t* __restrict__ hs2,  // [N][48]
                                                       const int* __restrict__ row_start,
                                                       const int* __restrict__ sorted_src,
                                                       const float* __restrict__ dinv,
                                                       const float* __restrict__ b1,
                                                       float* __restrict__ g) {
    int tid = threadIdx.x;
    int wave = tid >> 6;
    int j = tid & 63;
    bool act = j < H1P;
    float b0 = 0.0f, b1v = 0.0f;
    if (act) { b0 = b1[2 * j]; b1v = b1[2 * j + 1]; }
    float g0 = 0.0f, g1 = 0.0f;

    int wid = blockIdx.x * 4 + wave;
    int nw = gridDim.x * 4;
    for (int n = wid; n < N_NODES; n += nw) {
        float a0 = 0.0f, a1 = 0.0f;
        if (act) {
            uint32_t v = hs2[n * H1P + j];  // self-loop term
            a0 = bf_lo(v); a1 = bf_hi(v);
        }
        int e = row_start[n];
        int ee = row_start[n + 1];
        for (; e + 4 <= ee; e += 4) {
            int s0 = sorted_src[e];
            int s1 = sorted_src[e + 1];
            int s2 = sorted_src[e + 2];
            int s3 = sorted_src[e + 3];
            if (act) {
                uint32_t v0 = hs2[s0 * H1P + j];
                uint32_t v1 = hs2[s1 * H1P + j];
                uint32_t v2 = hs2[s2 * H1P + j];
                uint32_t v3 = hs2[s3 * H1P + j];
                a0 += (bf_lo(v0) + bf_lo(v1)) + (bf_lo(v2) + bf_lo(v3));
                a1 += (bf_hi(v0) + bf_hi(v1)) + (bf_hi(v2) + bf_hi(v3));
            }
        }
        for (; e < ee; ++e) {
            int s = sorted_src[e];
            if (act) {
                uint32_t v = hs2[s * H1P + j];
                a0 += bf_lo(v); a1 += bf_hi(v);
            }
        }
        float dv = dinv[n];
        if (act) {
            g0 += fmaxf(fmaf(dv, a0, b0), 0.0f);
            g1 += fmaxf(fmaf(dv, a1, b1v), 0.0f);
        }
    }

    __shared__ float sg[H1];
    if (wave == 0 && act) { sg[2 * j] = g0; sg[2 * j + 1] = g1; }
    __syncthreads();
    if (wave != 0 && act) {
        atomicAdd(&sg[2 * j], g0);
        atomicAdd(&sg[2 * j + 1], g1);
    }
    __syncthreads();
    if (wave == 0 && act) {
        atomicAdd(&g[2 * j], sg[2 * j]);
        atomicAdd(&g[2 * j + 1], sg[2 * j + 1]);
    }
}

// ---------------- tiny MLP head ----------------
__global__ void mlp_kernel(const float* __restrict__ g,
                           const float* __restrict__ lw1, const float* __restrict__ lb1,
                           const float* __restrict__ lw2, const float* __restrict__ lb2,
                           const float* __restrict__ lw3, const float* __restrict__ lb3,
                           float* __restrict__ out) {
    __shared__ float sg[H1], v1[H1], v2[H2];
    int t = threadIdx.x;  // blockDim = 128
    if (t < H1) sg[t] = g[t];
    __syncthreads();
    if (t < H1) {
        float a = lb1[t];
        for (int k = 0; k < H1; ++k) a = fmaf(sg[k], lw1[k * H1 + t], a);
        v1[t] = fmaxf(a, 0.0f);
    }
    __syncthreads();
    if (t < H2) {
        float a = lb2[t];
        for (int k = 0; k < H1; ++k) a = fmaf(v1[k], lw2[k * H2 + t], a);
        v2[t] = fmaxf(a, 0.0f);
    }
    __syncthreads();
    if (t == 0) {
        float a = lb3[0];
        for (int k = 0; k < H2; ++k) a = fmaf(v2[k], lw3[k], a);
        out[0] = a;
    }
}

extern "C" void kernel_launch(void* const* d_in, const int* in_sizes, int n_in,
                              void* d_out, int out_size, void* d_ws, size_t ws_size,
                              hipStream_t stream) {
    const float* x   = (const float*)d_in[0];
    const int*   ei  = (const int*)d_in[1];      // [2, N_EDGES] int32
    const float* W1  = (const float*)d_in[2];
    const float* b1  = (const float*)d_in[3];
    const float* lw1 = (const float*)d_in[4];
    const float* lb1 = (const float*)d_in[5];
    const float* lw2 = (const float*)d_in[6];
    const float* lb2 = (const float*)d_in[7];
    const float* lw3 = (const float*)d_in[8];
    const float* lb3 = (const float*)d_in[9];
    float* out = (float*)d_out;

    const int* src = ei;
    const int* dst = ei + N_EDGES;

    char* ws = (char*)d_ws;
    size_t off = 0;
    auto alloc = [&](size_t bytes) {
        char* p = ws + off;
        off = (off + bytes + 255) & ~(size_t)255;
        return p;
    };
    int*      deg        = (int*)alloc((size_t)N_NODES * sizeof(int));
    float*    g          = (float*)alloc((size_t)H1 * sizeof(float));
    float*    dinv       = (float*)alloc((size_t)N_NODES * sizeof(float));
    int*      row_start  = (int*)alloc((size_t)(N_NODES + 1) * sizeof(int));
    int*      cursor     = (int*)alloc((size_t)N_NODES * sizeof(int));
    int*      block_sums = (int*)alloc((size_t)N_SBLK * sizeof(int));
    int*      sorted_src = (int*)alloc((size_t)N_EDGES * sizeof(int));
    uint16_t* hs         = (uint16_t*)alloc((size_t)N_NODES * H1 * sizeof(uint16_t));
    (void)ws_size;

    hipMemsetAsync(deg, 0, (char*)(g + H1) - (char*)deg, stream);

    count_deg_kernel<<<2048, 256, 0, stream>>>(dst, deg);
    deg_part_kernel<<<N_SBLK, SCAN_BLK, 0, stream>>>(deg, block_sums);
    block_scan_kernel<<<1, SCAN_BLK, 0, stream>>>(block_sums);
    deg_scan_kernel<<<N_SBLK, SCAN_BLK, 0, stream>>>(deg, block_sums, row_start, cursor, dinv);
    scatter_kernel<<<2048, 256, 0, stream>>>(src, dst, cursor, sorted_src);

    gemm_kernel<<<(N_NODES + GEMM_NODES - 1) / GEMM_NODES, 256, 0, stream>>>(x, W1, dinv, hs);

    agg_pool_kernel<<<2048, 256, 0, stream>>>((const uint32_t*)hs, row_start, sorted_src, dinv, b1, g);

    mlp_kernel<<<1, 128, 0, stream>>>(g, lw1, lb1, lw2, lb2, lw3, lb3, out);
}